// Round 11
// baseline (220.135 us; speedup 1.0000x reference)
//
#include <hip/hip_runtime.h>
#include <math.h>

#define DIM   1024
#define NH    16
#define NG    4
#define HD    64
#define SEQ   2048
#define NB    2
#define SCALE 0.125f
#define LN_EPS 1e-5f
#define LOG2E 1.44269504f
#define QS    (SCALE * LOG2E)   // Q pre-scale so scores are in log2 space
// No fixed-max subtraction: |S2| <= 11.6 so exp2(S2) <= ~3100, safe in fp32/bf16.

#if __has_builtin(__builtin_amdgcn_exp2f)
#define EXP2F(x) __builtin_amdgcn_exp2f(x)
#else
#define EXP2F(x) __expf((x) * 0.69314718f)
#endif

typedef __attribute__((ext_vector_type(8)))  short short8;
typedef __attribute__((ext_vector_type(4)))  short short4v;
typedef __attribute__((ext_vector_type(4)))  float f32x4;
typedef __attribute__((ext_vector_type(16))) float f32x16;
typedef __attribute__((ext_vector_type(4)))  uint  uint4v;
typedef unsigned short ushort;
typedef unsigned int uint;

__device__ __forceinline__ ushort f2b(float f) {
  uint u = __builtin_bit_cast(uint, f);
  u += 0x7FFFu + ((u >> 16) & 1u);            // RNE
  return (ushort)(u >> 16);
}
__device__ __forceinline__ uint pack2(float a, float b) {   // RNE pair
  return (uint)f2b(a) | ((uint)f2b(b) << 16);
}
// truncation pack: lo16 = bf16_trunc(a), hi16 = bf16_trunc(b); 1 inst
__device__ __forceinline__ uint packtr(float a, float b) {
  return __builtin_amdgcn_perm(__builtin_bit_cast(uint, b),
                               __builtin_bit_cast(uint, a), 0x07060302u);
}
__device__ __forceinline__ void gload16(const void* g, void* l) {
  __builtin_amdgcn_global_load_lds(
      (const __attribute__((address_space(1))) void*)g,
      (__attribute__((address_space(3))) void*)l, 16, 0, 0);
}

// ---------------- fp32 -> bf16 cast, 7 segments, 2048 el/block ---------------
struct CastSeg { const float* s; ushort* d; int nblk; };
struct CastArgs { CastSeg seg[7]; };

__global__ __launch_bounds__(256) void castN(CastArgs a) {
  int t = blockIdx.x, i = 0;
  while (i < 6 && t >= a.seg[i].nblk) { t -= a.seg[i].nblk; ++i; }
  const float* src = a.seg[i].s;
  ushort* dst = a.seg[i].d;
  size_t idx = (size_t)t * 2048 + threadIdx.x * 8;
  float4 f0 = *(const float4*)(src + idx);
  float4 f1 = *(const float4*)(src + idx + 4);
  short8 o;
  o[0] = (short)f2b(f0.x); o[1] = (short)f2b(f0.y);
  o[2] = (short)f2b(f0.z); o[3] = (short)f2b(f0.w);
  o[4] = (short)f2b(f1.x); o[5] = (short)f2b(f1.y);
  o[6] = (short)f2b(f1.z); o[7] = (short)f2b(f1.w);
  *(short8*)(dst + idx) = o;
}

// ---- staging: 64-col bf16 tile rows, XOR-swizzled, width-16 DMA, k-offset ----
#define STAGE2(dstLDS, srcG, NROWS, kk)                                        \
  _Pragma("unroll")                                                            \
  for (int i = 0; i < (NROWS) / 32; ++i) {                                     \
    int s = i * 256 + tid;                                                     \
    int row = s >> 3, cg = (s & 7) ^ (row & 7);                                \
    gload16(&(srcG)[(size_t)row * DIM + (kk) + cg * 8],                        \
            &(dstLDS)[(size_t)(i * 256 + (wave << 6)) * 8]);                   \
  }

// 128x64 GEMM core, double-buffered LDS ping-pong: DMA for tile k+1 is issued
// before computing tile k, so the pre-barrier vmcnt(0) drain is ~free.
#define CORE_128x64(Aptr, Wbase)                                               \
  f32x4 acc[2][4] = {};                                                        \
  { const int wm0 = wave * 32;                                                 \
    const ushort* Arows = (Aptr) + (size_t)m0 * DIM;                           \
    STAGE2(As[0], Arows, 128, 0)                                               \
    STAGE2(Ws[0], (Wbase), 64, 0)                                              \
    _Pragma("unroll")                                                          \
    for (int k0 = 0; k0 < DIM; k0 += 64) {                                     \
      const int pb = (k0 >> 6) & 1;                                            \
      __syncthreads();                                                         \
      if (k0 + 64 < DIM) {                                                     \
        STAGE2(As[1 - pb], Arows, 128, k0 + 64)                                \
        STAGE2(Ws[1 - pb], (Wbase), 64, k0 + 64)                               \
      }                                                                        \
      _Pragma("unroll")                                                        \
      for (int kh = 0; kh < 2; ++kh) {                                         \
        short8 af[2], bfr[4];                                                  \
        _Pragma("unroll")                                                      \
        for (int mt = 0; mt < 2; ++mt) {                                       \
          int row = wm0 + mt * 16 + l16;                                       \
          int st = (kh * 4 + quad) ^ (row & 7);                                \
          af[mt] = *(const short8*)&As[pb][row * 64 + st * 8];                 \
        }                                                                      \
        _Pragma("unroll")                                                      \
        for (int nt = 0; nt < 4; ++nt) {                                       \
          int row = nt * 16 + l16;                                             \
          int st = (kh * 4 + quad) ^ (row & 7);                                \
          bfr[nt] = *(const short8*)&Ws[pb][row * 64 + st * 8];                \
        }                                                                      \
        _Pragma("unroll")                                                      \
        for (int mt = 0; mt < 2; ++mt)                                         \
          _Pragma("unroll")                                                    \
          for (int nt = 0; nt < 4; ++nt)                                       \
            acc[mt][nt] = __builtin_amdgcn_mfma_f32_16x16x32_bf16(             \
                af[mt], bfr[nt], acc[mt][nt], 0, 0, 0);                        \
      }                                                                        \
    } }

// LayerNorm epilogue over one 64-col head (cols colb..colb+63), rows per MT
#define LN_EPI(MT, rowbase, biasp, lnwp, lnbp, psv, outp, ostride, colb)       \
  { float bw[4], lw[4], lb[4];                                                 \
    _Pragma("unroll") for (int nt = 0; nt < 4; ++nt) {                         \
      bw[nt] = biasp[(colb) + nt * 16 + l16];                                  \
      lw[nt] = lnwp[nt * 16 + l16];                                            \
      lb[nt] = lnbp[nt * 16 + l16]; }                                          \
    _Pragma("unroll") for (int mt = 0; mt < (MT); ++mt) {                      \
      _Pragma("unroll") for (int r = 0; r < 4; ++r) {                          \
        float x0 = acc[mt][0][r] + bw[0];                                      \
        float x1 = acc[mt][1][r] + bw[1];                                      \
        float x2 = acc[mt][2][r] + bw[2];                                      \
        float x3 = acc[mt][3][r] + bw[3];                                      \
        float s1 = x0 + x1 + x2 + x3;                                          \
        float s2 = x0 * x0 + x1 * x1 + x2 * x2 + x3 * x3;                      \
        _Pragma("unroll") for (int off = 1; off < 16; off <<= 1) {             \
          s1 += __shfl_xor(s1, off, 64); s2 += __shfl_xor(s2, off, 64); }      \
        float mean = s1 * (1.f / 64.f);                                        \
        float var  = s2 * (1.f / 64.f) - mean * mean;                          \
        float inv  = rsqrtf(var + LN_EPS);                                     \
        int row = (rowbase) + mt * 16 + quad * 4 + r;                          \
        ushort* dst = outp + (size_t)row * (ostride) + (colb) + l16;           \
        dst[ 0] = f2b(((x0 - mean) * inv * lw[0] + lb[0]) * (psv));            \
        dst[16] = f2b(((x1 - mean) * inv * lw[1] + lb[1]) * (psv));            \
        dst[32] = f2b(((x2 - mean) * inv * lw[2] + lb[2]) * (psv));            \
        dst[48] = f2b(((x3 - mean) * inv * lw[3] + lb[3]) * (psv)); } } }

// ---- fused QKV projections, uniform 128x64 tiles, 768 balanced blocks ------
// 1-D grid, XCD-chunked bijective swizzle (768 % 8 == 0). Per swizzled id:
// x = sw % 24 (0..15 Q head-tiles, 16..19 K, 20..23 V), y = sw / 24 (row-tile).
// 48 KB LDS -> 3 blocks/CU (perfectly balanced: all blocks identical work).
__global__ __launch_bounds__(256) void gemm_qkv(
    const ushort* __restrict__ qA, const ushort* __restrict__ kA,
    const ushort* __restrict__ vA,
    const ushort* __restrict__ WqB, const ushort* __restrict__ WkB,
    const ushort* __restrict__ WvB,
    const float* __restrict__ bq, const float* __restrict__ bk,
    const float* __restrict__ bv,
    const float* __restrict__ qnw, const float* __restrict__ qnb,
    const float* __restrict__ knw, const float* __restrict__ knb,
    ushort* __restrict__ Qb, ushort* __restrict__ kbb, ushort* __restrict__ vtb)
{
  __shared__ __align__(16) ushort As[2][128 * 64];   // 32 KB
  __shared__ __align__(16) ushort Ws[2][64 * 64];    // 16 KB
  const int bid = blockIdx.x;
  const int sw = (bid & 7) * 96 + (bid >> 3);   // XCD chunk: 24 x-tiles x 4 y-tiles
  const int x = sw % 24;
  const int tid = threadIdx.x;
  const int wave = tid >> 6, lane = tid & 63;
  const int quad = lane >> 4, l16 = lane & 15;
  const int m0 = (sw / 24) * 128;

  if (x < 16) {           // ---- Q projection: one 64-wide head, LN epilogue
    const ushort* Wbase = WqB + (size_t)x * 64 * DIM;
    CORE_128x64(qA, Wbase)
    LN_EPI(2, m0 + wave * 32, bq, qnw, qnb, QS, Qb, DIM, x * 64)
  } else if (x < 20) {    // ---- K projection, LN epilogue
    const int n0 = (x - 16) * 64;
    const ushort* Wbase = WkB + (size_t)n0 * DIM;
    CORE_128x64(kA, Wbase)
    LN_EPI(2, m0 + wave * 32, bk, knw, knb, 1.0f, kbb, NG * HD, n0)
  } else {                // ---- V projection, permuted transpose-scatter
    const int g = x - 20;
    const ushort* Wbase = WvB + (size_t)g * 64 * DIM;
    CORE_128x64(vA, Wbase)
#pragma unroll
    for (int nt = 0; nt < 4; ++nt) {
      int d = nt * 16 + l16;
      float bvv = bv[g * 64 + d];
#pragma unroll
      for (int mt = 0; mt < 2; ++mt)
#pragma unroll
        for (int r = 0; r < 4; ++r) {
          int row = m0 + wave * 32 + mt * 16 + quad * 4 + r;   // b*SEQ + kv
          int bb = row >> 11, kv = row & (SEQ - 1);
          // swap bits 2<->3 within each kv-16 block so P's MFMA C-layout
          // registers line up with B-operand k-slots (no lane exchange)
          int kvp = (kv & ~12) | ((kv & 4) << 1) | ((kv & 8) >> 1);
          vtb[((size_t)(bb * NG + g) * HD + d) * SEQ + kvp] =
              f2b(acc[mt][nt][r] + bvv);
        }
    }
  }
}

// ---------------- output projection, 128x64 -> fp32 ----------------
// 1-D grid 512, XCD row-chunk swizzle (512 % 8 == 0): XCD c gets row-panels
// 4c..4c+3 across all 16 col-tiles -> A-row panels and Wo stay in one L2.
__global__ __launch_bounds__(256) void gemm_out(
    const ushort* __restrict__ A, const ushort* __restrict__ WoB,
    const float* __restrict__ bo, float* __restrict__ Cf)
{
  __shared__ __align__(16) ushort As[2][128 * 64];   // 32 KB
  __shared__ __align__(16) ushort Ws[2][64 * 64];    // 16 KB
  const int bid = blockIdx.x;
  const int sw = (bid & 7) * 64 + (bid >> 3);   // row-major (row, col) chunks
  const int tid = threadIdx.x;
  const int wave = tid >> 6, lane = tid & 63;
  const int quad = lane >> 4, l16 = lane & 15;
  const int m0 = (sw >> 4) * 128;
  const int n0 = (sw & 15) * 64;
  const ushort* Wbase = WoB + (size_t)n0 * DIM;
  CORE_128x64(A, Wbase)
#pragma unroll
  for (int nt = 0; nt < 4; ++nt) {
    int col = n0 + nt * 16 + l16;
    float bvv = bo[col];
#pragma unroll
    for (int mt = 0; mt < 2; ++mt)
#pragma unroll
      for (int r = 0; r < 4; ++r) {
        int row = m0 + wave * 32 + mt * 16 + quad * 4 + r;
        Cf[(size_t)row * DIM + col] = acc[mt][nt][r] + bvv;
      }
  }
}

// ------- Flash attention, S^T = K Q^T, kv-tile 128, kv-split wave pairs -----
// 512 blocks x 512 thr (8 waves): wave (qw=wave&3, kh=wave>>2) computes
// q-subtile qw (32 q) over kv-HALF kh (64 kv rows of the 128-tile). Same 512
// blocks / 2 blocks/CU / 16-tile loop / staging as the 219.9us baseline, but
// waves/SIMD 2->4 (TLP doubling at constant barrier structure) and per-wave
// serial chain per tile halves. No-max softmax => partials combine by PLAIN
// ADDITION of O and lsum (one LDS round-trip at the end).
// 1-D grid, XCD-exclusive decode — bid&7 -> (b,g) (FETCH 6.2 MB measured).
// V^T rows are kv-permuted (bits 2<->3 per 16-block) so each lane's S C-layout
// registers ARE its P B-fragment.
__global__ __launch_bounds__(512, 4) void attn_mfma4(
    const ushort* __restrict__ qb,   // [B,SEQ,1024] bf16, LN'd, *QS
    const ushort* __restrict__ kb,   // [B,SEQ,256] bf16, LN'd
    const ushort* __restrict__ vt,   // [B*NG*64][SEQ] bf16, kv-permuted V^T
    ushort* __restrict__ op)         // [B,SEQ,1024] bf16
{
  __shared__ __align__(16) ushort SM[2][16384];  // 64 KB: 2x{ Ks(16K) | Vs(16K) }
  const int bid = blockIdx.x;
  const int xcd = bid & 7, rest = bid >> 3;     // 512 blocks: 8 XCD x 64
  const int b = xcd >> 2, g = xcd & 3;          // one (b,g) per XCD
  const int h = g * 4 + (rest & 3);
  const int qt = rest >> 2;                     // 0..15
  const int tid = threadIdx.x;
  const int wave = tid >> 6, lane = tid & 63;
  const int qw = wave & 3, kh = wave >> 2;      // q sub-tile / kv half
  const int l32 = lane & 31, hf = lane >> 5;
  const int q0 = qt << 7;

  // Q B-operand frags: n = q = l32, k = hf*8 + j (per 16-wide k-step)
  short8 qf[4];
  {
    const ushort* qp = qb + (size_t)(b * SEQ + q0 + qw * 32 + l32) * DIM
                          + h * HD + hf * 8;
#pragma unroll
    for (int ks = 0; ks < 4; ++ks) qf[ks] = *(const short8*)(qp + ks * 16);
  }

  // stage K [128 kv][64 d] and permuted V^T [64 d][128 kv] into buffer PB
  // (512 threads: 2 iterations cover each 1024x16B tile; linear dest)
#define STAGE_ATTN(PB, KV0)                                                    \
  _Pragma("unroll")                                                            \
  for (int i = 0; i < 2; ++i) {                                                \
    int s = i * 512 + tid;                                                     \
    int rowK = s >> 3, cgK = (s & 7) ^ (rowK & 7);                             \
    gload16(&kb[(size_t)(b * SEQ + (KV0) + rowK) * (NG * HD) + g * HD + cgK * 8],\
            &SM[PB][(size_t)(i * 512 + (wave << 6)) * 8]);                     \
    int rowV = s >> 4, cgV = (s & 15) ^ (rowV & 7);                            \
    gload16(&vt[((size_t)(b * NG + g) * HD + rowV) * SEQ + (KV0) + cgV * 8],   \
            &SM[PB][8192 + (size_t)(i * 512 + (wave << 6)) * 8]);              \
  }

  f32x16 O0 = {0,0,0,0,0,0,0,0,0,0,0,0,0,0,0,0};  // O^T[d 0..31][q], kv-half kh
  f32x16 O1 = {0,0,0,0,0,0,0,0,0,0,0,0,0,0,0,0};  // O^T[d 32..63][q]
  float lsum = 0.f;

  STAGE_ATTN(0, 0)
  __syncthreads();   // vmcnt(0) drain: tile 0 resident

  for (int kv0 = 0; kv0 < SEQ; kv0 += 128) {
    const int pb = (kv0 >> 7) & 1;
    if (kv0 + 128 < SEQ) { STAGE_ATTN(1 - pb, kv0 + 128) }  // async, in flight
    const ushort* Ks = SM[pb] + kh * 64 * 64;   // this wave's 64 kv rows
    const ushort* Vs = SM[pb] + 8192;

    // S^T = K Q^T over this wave's kv half: 2x 32-kv blocks
    f32x16 S0 = {0,0,0,0,0,0,0,0,0,0,0,0,0,0,0,0};
    f32x16 S1 = {0,0,0,0,0,0,0,0,0,0,0,0,0,0,0,0};
    __builtin_amdgcn_s_setprio(1);
#pragma unroll
    for (int ks = 0; ks < 4; ++ks) {
      short8 k0 = *(const short8*)&Ks[( 0 + l32) * 64 + (((ks*2+hf) ^ (l32 & 7)) * 8)];
      short8 k1 = *(const short8*)&Ks[(32 + l32) * 64 + (((ks*2+hf) ^ (l32 & 7)) * 8)];
      S0 = __builtin_amdgcn_mfma_f32_32x32x16_bf16(k0, qf[ks], S0, 0, 0, 0);
      S1 = __builtin_amdgcn_mfma_f32_32x32x16_bf16(k1, qf[ks], S1, 0, 0, 0);
    }
    __builtin_amdgcn_s_setprio(0);

    // softmax + PV over this wave's 4 kv-16 blocks
#pragma unroll
    for (int t = 0; t < 4; ++t) {
      const f32x16& Ss = (t < 2) ? S0 : S1;
      int base = (t & 1) * 8;
      float e0 = EXP2F(Ss[base + 0]), e1 = EXP2F(Ss[base + 1]);
      float e2 = EXP2F(Ss[base + 2]), e3 = EXP2F(Ss[base + 3]);
      float e4 = EXP2F(Ss[base + 4]), e5 = EXP2F(Ss[base + 5]);
      float e6 = EXP2F(Ss[base + 6]), e7 = EXP2F(Ss[base + 7]);
      lsum += ((e0 + e1) + (e2 + e3)) + ((e4 + e5) + (e6 + e7));
      uint4v pw;
      pw[0] = packtr(e0, e1); pw[1] = packtr(e2, e3);
      pw[2] = packtr(e4, e5); pw[3] = packtr(e6, e7);
      short8 pf = __builtin_bit_cast(short8, pw);
      int ch = (kh * 4 + t) * 2 + hf;           // global kv-16 block col-group
      short8 v0 = *(const short8*)&Vs[( 0 + l32) * 128 + ((ch ^ (l32 & 7)) * 8)];
      short8 v1 = *(const short8*)&Vs[(32 + l32) * 128 + ((ch ^ (l32 & 7)) * 8)];
      __builtin_amdgcn_s_setprio(1);
      O0 = __builtin_amdgcn_mfma_f32_32x32x16_bf16(v0, pf, O0, 0, 0, 0);
      O1 = __builtin_amdgcn_mfma_f32_32x32x16_bf16(v1, pf, O1, 0, 0, 0);
      __builtin_amdgcn_s_setprio(0);
    }
    // single per-tile barrier: drains this tile's prefetch DMA (vmcnt) and
    // fences all waves' LDS reads before buffer 1-pb is restaged next iter
    __syncthreads();
  }

  // ---- kv-half combine: plain addition (no-max softmax). kh==1 waves park
  // their partials in LDS; kh==0 waves add and finish. red region starts after
  // the 4 Lw transpose regions (byte 17408) — disjoint, no extra barrier.
  float* red = (float*)((ushort*)SM + 4 * 32 * 68);
  {
    float* me = red + (size_t)(qw * 64 + lane) * 33;   // stride 33: bank-clean
    if (kh == 1) {
#pragma unroll
      for (int r = 0; r < 16; ++r) { me[r] = O0[r]; me[16 + r] = O1[r]; }
      me[32] = lsum;
    }
  }
  __syncthreads();
  if (kh == 1) return;   // no barriers after this point

  {
    const float* pr = red + (size_t)(qw * 64 + lane) * 33;
#pragma unroll
    for (int r = 0; r < 16; ++r) { O0[r] += pr[r]; O1[r] += pr[16 + r]; }
    lsum += pr[32];
  }

  float inv = 1.f / (lsum + __shfl_xor(lsum, 32, 64));

  // transpose O^T -> O via LDS (wave-private region, stride 68)
  ushort* Lw = (ushort*)SM + qw * (32 * 68);
#pragma unroll
  for (int r = 0; r < 16; r += 2) {
    int d0 = (r & 3) + 8 * (r >> 2) + 4 * hf;
    *(uint*)&Lw[l32 * 68 + d0]      = pack2(O0[r] * inv, O0[r + 1] * inv);
    *(uint*)&Lw[l32 * 68 + 32 + d0] = pack2(O1[r] * inv, O1[r + 1] * inv);
  }
  // each lane writes row q=l32, d-half hf (wave-private: no barrier needed)
  ushort* orow = op + (size_t)(b * SEQ + q0 + qw * 32 + l32) * DIM
                    + h * HD + hf * 32;
#pragma unroll
  for (int c = 0; c < 4; ++c) {
    short4v lo = *(const short4v*)&Lw[l32 * 68 + hf * 32 + c * 8];
    short4v hi = *(const short4v*)&Lw[l32 * 68 + hf * 32 + c * 8 + 4];
    short8 o = {lo[0], lo[1], lo[2], lo[3], hi[0], hi[1], hi[2], hi[3]};
    *(short8*)(orow + c * 8) = o;
  }
#undef STAGE_ATTN
}

extern "C" void kernel_launch(void* const* d_in, const int* in_sizes, int n_in,
                              void* d_out, int out_size, void* d_ws, size_t ws_size,
                              hipStream_t stream) {
  (void)in_sizes; (void)n_in; (void)out_size; (void)ws_size;
  const float* query = (const float*)d_in[0];
  const float* key   = (const float*)d_in[1];
  const float* value = (const float*)d_in[2];
  const float* Wq = (const float*)d_in[4];
  const float* bq = (const float*)d_in[5];
  const float* Wk = (const float*)d_in[6];
  const float* bk = (const float*)d_in[7];
  const float* Wv = (const float*)d_in[8];
  const float* bv = (const float*)d_in[9];
  const float* qnw = (const float*)d_in[10];
  const float* qnb = (const float*)d_in[11];
  const float* knw = (const float*)d_in[12];
  const float* knb = (const float*)d_in[13];
  const float* Wo = (const float*)d_in[14];
  const float* bo = (const float*)d_in[15];
  float* out = (float*)d_out;

  const size_t MD = (size_t)NB * SEQ * DIM;        // 4M elements
  const size_t WD = (size_t)DIM * DIM;             // 1M
  const size_t KD = (size_t)(NG * HD) * DIM;       // 256K
  const size_t MK = (size_t)NB * SEQ * NG * HD;    // 1M

  // ws (29 MB):
  ushort* qA  = (ushort*)d_ws;        // 8 MB
  ushort* kA  = qA  + MD;             // 8 MB (later: attention output)
  ushort* WqB = kA  + MD;             // 2 MB
  ushort* WkB = WqB + WD;             // 0.5 MB
  ushort* WvB = WkB + KD;             // 0.5 MB
  ushort* WoB = WvB + KD;             // 2 MB
  ushort* Qb  = WoB + WD;             // 8 MB
  // d_out as scratch (12 of 16 MB), all dead before gemm_out writes:
  ushort* vA  = (ushort*)d_out;       // 8 MB
  ushort* kbb = vA  + MD;             // 2 MB
  ushort* vtb = kbb + MK;             // 2 MB
  ushort* attnO = kA;

  dim3 blk(256);
  CastArgs ca;
  ca.seg[0] = { query, qA, 2048 };
  ca.seg[1] = { key,   kA, 2048 };
  ca.seg[2] = { value, vA, 2048 };
  ca.seg[3] = { Wq, WqB, 512 };
  ca.seg[4] = { Wk, WkB, 128 };
  ca.seg[5] = { Wv, WvB, 128 };
  ca.seg[6] = { Wo, WoB, 512 };
  castN<<<dim3(7424), blk, 0, stream>>>(ca);
  gemm_qkv<<<dim3(768), blk, 0, stream>>>(
      qA, kA, vA, WqB, WkB, WvB, bq, bk, bv,
      qnw, qnb, knw, knb, Qb, kbb, vtb);
  attn_mfma4<<<dim3(512), dim3(512), 0, stream>>>(Qb, kbb, vtb, attnO);
  gemm_out<<<dim3(512), blk, 0, stream>>>(attnO, WoB, bo, out);
}

// Round 12
// 216.777 us; speedup vs baseline: 1.0155x; 1.0155x over previous
//
#include <hip/hip_runtime.h>
#include <math.h>

#define DIM   1024
#define NH    16
#define NG    4
#define HD    64
#define SEQ   2048
#define NB    2
#define SCALE 0.125f
#define LN_EPS 1e-5f
#define LOG2E 1.44269504f
#define QS    (SCALE * LOG2E)   // Q pre-scale so scores are in log2 space
// No fixed-max subtraction: |S2| <= 11.6 so exp2(S2) <= ~3100, safe in fp32/bf16.

#if __has_builtin(__builtin_amdgcn_exp2f)
#define EXP2F(x) __builtin_amdgcn_exp2f(x)
#else
#define EXP2F(x) __expf((x) * 0.69314718f)
#endif

typedef __attribute__((ext_vector_type(8)))  short short8;
typedef __attribute__((ext_vector_type(4)))  short short4v;
typedef __attribute__((ext_vector_type(4)))  float f32x4;
typedef __attribute__((ext_vector_type(16))) float f32x16;
typedef __attribute__((ext_vector_type(4)))  uint  uint4v;
typedef unsigned short ushort;
typedef unsigned int uint;

__device__ __forceinline__ ushort f2b(float f) {
  uint u = __builtin_bit_cast(uint, f);
  u += 0x7FFFu + ((u >> 16) & 1u);            // RNE
  return (ushort)(u >> 16);
}
__device__ __forceinline__ uint pack2(float a, float b) {   // RNE pair
  return (uint)f2b(a) | ((uint)f2b(b) << 16);
}
// truncation pack: lo16 = bf16_trunc(a), hi16 = bf16_trunc(b); 1 inst
__device__ __forceinline__ uint packtr(float a, float b) {
  return __builtin_amdgcn_perm(__builtin_bit_cast(uint, b),
                               __builtin_bit_cast(uint, a), 0x07060302u);
}
__device__ __forceinline__ void gload16(const void* g, void* l) {
  __builtin_amdgcn_global_load_lds(
      (const __attribute__((address_space(1))) void*)g,
      (__attribute__((address_space(3))) void*)l, 16, 0, 0);
}

// ---------------- fp32 -> bf16 cast, 7 segments, 2048 el/block ---------------
struct CastSeg { const float* s; ushort* d; int nblk; };
struct CastArgs { CastSeg seg[7]; };

__global__ __launch_bounds__(256) void castN(CastArgs a) {
  int t = blockIdx.x, i = 0;
  while (i < 6 && t >= a.seg[i].nblk) { t -= a.seg[i].nblk; ++i; }
  const float* src = a.seg[i].s;
  ushort* dst = a.seg[i].d;
  size_t idx = (size_t)t * 2048 + threadIdx.x * 8;
  float4 f0 = *(const float4*)(src + idx);
  float4 f1 = *(const float4*)(src + idx + 4);
  short8 o;
  o[0] = (short)f2b(f0.x); o[1] = (short)f2b(f0.y);
  o[2] = (short)f2b(f0.z); o[3] = (short)f2b(f0.w);
  o[4] = (short)f2b(f1.x); o[5] = (short)f2b(f1.y);
  o[6] = (short)f2b(f1.z); o[7] = (short)f2b(f1.w);
  *(short8*)(dst + idx) = o;
}

// -- staging, 512-thread blocks: 64-col bf16 rows, XOR-swizzled, 16B DMA -----
// dest is wave-uniform base + lane*16 (linear); source per-lane swizzled.
#define STAGE2W(dstLDS, srcG, NROWS, kk)                                       \
  _Pragma("unroll")                                                            \
  for (int i = 0; i < (NROWS) / 64; ++i) {                                     \
    int s = i * 512 + tid;                                                     \
    int row = s >> 3, cg = (s & 7) ^ (row & 7);                                \
    gload16(&(srcG)[(size_t)row * DIM + (kk) + cg * 8],                        \
            &(dstLDS)[(size_t)(i * 512 + (wave << 6)) * 8]);                   \
  }

// 128x64 GEMM core, 8 waves (R12): each wave owns 16 output rows (acc[1][4])
// -> per-wave MFMA chain per K-step halves, waves/SIMD doubles vs the 4-wave
// version (R11-validated TLP lever), no combine needed (disjoint rows).
// Same tile, grid, barrier count, double-buffered ping-pong as the 219.9us
// baseline. Requires in scope: tid, wave, quad, l16, m0.
#define CORE_128x64W(Aptr, Wbase)                                              \
  f32x4 acc[1][4] = {};                                                        \
  { const int wm0 = wave * 16;                                                 \
    const ushort* Arows = (Aptr) + (size_t)m0 * DIM;                           \
    STAGE2W(As[0], Arows, 128, 0)                                              \
    STAGE2W(Ws[0], (Wbase), 64, 0)                                             \
    _Pragma("unroll")                                                          \
    for (int k0 = 0; k0 < DIM; k0 += 64) {                                     \
      const int pb = (k0 >> 6) & 1;                                            \
      __syncthreads();                                                         \
      if (k0 + 64 < DIM) {                                                     \
        STAGE2W(As[1 - pb], Arows, 128, k0 + 64)                               \
        STAGE2W(Ws[1 - pb], (Wbase), 64, k0 + 64)                              \
      }                                                                        \
      _Pragma("unroll")                                                        \
      for (int kh = 0; kh < 2; ++kh) {                                         \
        short8 af, bfr[4];                                                     \
        { int row = wm0 + l16;                                                 \
          int st = (kh * 4 + quad) ^ (row & 7);                                \
          af = *(const short8*)&As[pb][row * 64 + st * 8]; }                   \
        _Pragma("unroll")                                                      \
        for (int nt = 0; nt < 4; ++nt) {                                       \
          int row = nt * 16 + l16;                                             \
          int st = (kh * 4 + quad) ^ (row & 7);                                \
          bfr[nt] = *(const short8*)&Ws[pb][row * 64 + st * 8];                \
        }                                                                      \
        _Pragma("unroll")                                                      \
        for (int nt = 0; nt < 4; ++nt)                                         \
          acc[0][nt] = __builtin_amdgcn_mfma_f32_16x16x32_bf16(                \
              af, bfr[nt], acc[0][nt], 0, 0, 0);                               \
      }                                                                        \
    } }

// LayerNorm epilogue over one 64-col head (cols colb..colb+63), rows per MT
#define LN_EPI(MT, rowbase, biasp, lnwp, lnbp, psv, outp, ostride, colb)       \
  { float bw[4], lw[4], lb[4];                                                 \
    _Pragma("unroll") for (int nt = 0; nt < 4; ++nt) {                         \
      bw[nt] = biasp[(colb) + nt * 16 + l16];                                  \
      lw[nt] = lnwp[nt * 16 + l16];                                            \
      lb[nt] = lnbp[nt * 16 + l16]; }                                          \
    _Pragma("unroll") for (int mt = 0; mt < (MT); ++mt) {                      \
      _Pragma("unroll") for (int r = 0; r < 4; ++r) {                          \
        float x0 = acc[mt][0][r] + bw[0];                                      \
        float x1 = acc[mt][1][r] + bw[1];                                      \
        float x2 = acc[mt][2][r] + bw[2];                                      \
        float x3 = acc[mt][3][r] + bw[3];                                      \
        float s1 = x0 + x1 + x2 + x3;                                          \
        float s2 = x0 * x0 + x1 * x1 + x2 * x2 + x3 * x3;                      \
        _Pragma("unroll") for (int off = 1; off < 16; off <<= 1) {             \
          s1 += __shfl_xor(s1, off, 64); s2 += __shfl_xor(s2, off, 64); }      \
        float mean = s1 * (1.f / 64.f);                                        \
        float var  = s2 * (1.f / 64.f) - mean * mean;                          \
        float inv  = rsqrtf(var + LN_EPS);                                     \
        int row = (rowbase) + mt * 16 + quad * 4 + r;                          \
        ushort* dst = outp + (size_t)row * (ostride) + (colb) + l16;           \
        dst[ 0] = f2b(((x0 - mean) * inv * lw[0] + lb[0]) * (psv));            \
        dst[16] = f2b(((x1 - mean) * inv * lw[1] + lb[1]) * (psv));            \
        dst[32] = f2b(((x2 - mean) * inv * lw[2] + lb[2]) * (psv));            \
        dst[48] = f2b(((x3 - mean) * inv * lw[3] + lb[3]) * (psv)); } } }

// ---- fused QKV projections, 128x64 tiles, 768 blocks x 512 thr -------------
// R5-proven grid/balance (3 blocks/CU LDS-bound, XCD-chunked), R12: 8 waves
// of 16 rows each -> 6 waves/SIMD (was 3). Same barriers/staging/tiles.
__global__ __launch_bounds__(512, 6) void gemm_qkv(
    const ushort* __restrict__ qA, const ushort* __restrict__ kA,
    const ushort* __restrict__ vA,
    const ushort* __restrict__ WqB, const ushort* __restrict__ WkB,
    const ushort* __restrict__ WvB,
    const float* __restrict__ bq, const float* __restrict__ bk,
    const float* __restrict__ bv,
    const float* __restrict__ qnw, const float* __restrict__ qnb,
    const float* __restrict__ knw, const float* __restrict__ knb,
    ushort* __restrict__ Qb, ushort* __restrict__ kbb, ushort* __restrict__ vtb)
{
  __shared__ __align__(16) ushort As[2][128 * 64];   // 32 KB
  __shared__ __align__(16) ushort Ws[2][64 * 64];    // 16 KB
  const int bid = blockIdx.x;
  const int sw = (bid & 7) * 96 + (bid >> 3);   // XCD chunk: 24 x-tiles x 4 y-tiles
  const int x = sw % 24;
  const int tid = threadIdx.x;
  const int wave = tid >> 6, lane = tid & 63;
  const int quad = lane >> 4, l16 = lane & 15;
  const int m0 = (sw / 24) * 128;

  if (x < 16) {           // ---- Q projection: one 64-wide head, LN epilogue
    const ushort* Wbase = WqB + (size_t)x * 64 * DIM;
    CORE_128x64W(qA, Wbase)
    LN_EPI(1, m0 + wave * 16, bq, qnw, qnb, QS, Qb, DIM, x * 64)
  } else if (x < 20) {    // ---- K projection, LN epilogue
    const int n0 = (x - 16) * 64;
    const ushort* Wbase = WkB + (size_t)n0 * DIM;
    CORE_128x64W(kA, Wbase)
    LN_EPI(1, m0 + wave * 16, bk, knw, knb, 1.0f, kbb, NG * HD, n0)
  } else {                // ---- V projection, permuted transpose-scatter
    const int g = x - 20;
    const ushort* Wbase = WvB + (size_t)g * 64 * DIM;
    CORE_128x64W(vA, Wbase)
#pragma unroll
    for (int nt = 0; nt < 4; ++nt) {
      int d = nt * 16 + l16;
      float bvv = bv[g * 64 + d];
#pragma unroll
      for (int r = 0; r < 4; ++r) {
        int row = m0 + wave * 16 + quad * 4 + r;   // b*SEQ + kv
        int bb = row >> 11, kv = row & (SEQ - 1);
        // swap bits 2<->3 within each kv-16 block so P's MFMA C-layout
        // registers line up with B-operand k-slots (no lane exchange)
        int kvp = (kv & ~12) | ((kv & 4) << 1) | ((kv & 8) >> 1);
        vtb[((size_t)(bb * NG + g) * HD + d) * SEQ + kvp] =
            f2b(acc[0][nt][r] + bvv);
      }
    }
  }
}

// ---------------- output projection, 128x64 -> fp32 ----------------
// 1-D grid 512 x 512 thr (2 blocks/CU -> 4 waves/SIMD, was 2), XCD row-chunk
// swizzle (512 % 8 == 0). R12: 8 waves of 16 rows each.
__global__ __launch_bounds__(512, 4) void gemm_out(
    const ushort* __restrict__ A, const ushort* __restrict__ WoB,
    const float* __restrict__ bo, float* __restrict__ Cf)
{
  __shared__ __align__(16) ushort As[2][128 * 64];   // 32 KB
  __shared__ __align__(16) ushort Ws[2][64 * 64];    // 16 KB
  const int bid = blockIdx.x;
  const int sw = (bid & 7) * 64 + (bid >> 3);   // row-major (row, col) chunks
  const int tid = threadIdx.x;
  const int wave = tid >> 6, lane = tid & 63;
  const int quad = lane >> 4, l16 = lane & 15;
  const int m0 = (sw >> 4) * 128;
  const int n0 = (sw & 15) * 64;
  const ushort* Wbase = WoB + (size_t)n0 * DIM;
  CORE_128x64W(A, Wbase)
#pragma unroll
  for (int nt = 0; nt < 4; ++nt) {
    int col = n0 + nt * 16 + l16;
    float bvv = bo[col];
#pragma unroll
    for (int r = 0; r < 4; ++r) {
      int row = m0 + wave * 16 + quad * 4 + r;
      Cf[(size_t)row * DIM + col] = acc[0][nt][r] + bvv;
    }
  }
}

// ------- Flash attention, S^T = K Q^T, kv-tile 128, kv-split wave pairs -----
// R11-proven (45.4 us): 512 blocks x 512 thr (8 waves): wave (qw=wave&3,
// kh=wave>>2) computes q-subtile qw (32 q) over kv-HALF kh. 2 blocks/CU,
// 4 waves/SIMD. No-max softmax => partials combine by PLAIN ADDITION.
// 1-D grid, XCD-exclusive decode — bid&7 -> (b,g) (FETCH 6.2 MB measured).
// V^T rows are kv-permuted (bits 2<->3 per 16-block) so each lane's S C-layout
// registers ARE its P B-fragment.
__global__ __launch_bounds__(512, 4) void attn_mfma4(
    const ushort* __restrict__ qb,   // [B,SEQ,1024] bf16, LN'd, *QS
    const ushort* __restrict__ kb,   // [B,SEQ,256] bf16, LN'd
    const ushort* __restrict__ vt,   // [B*NG*64][SEQ] bf16, kv-permuted V^T
    ushort* __restrict__ op)         // [B,SEQ,1024] bf16
{
  __shared__ __align__(16) ushort SM[2][16384];  // 64 KB: 2x{ Ks(16K) | Vs(16K) }
  const int bid = blockIdx.x;
  const int xcd = bid & 7, rest = bid >> 3;     // 512 blocks: 8 XCD x 64
  const int b = xcd >> 2, g = xcd & 3;          // one (b,g) per XCD
  const int h = g * 4 + (rest & 3);
  const int qt = rest >> 2;                     // 0..15
  const int tid = threadIdx.x;
  const int wave = tid >> 6, lane = tid & 63;
  const int qw = wave & 3, kh = wave >> 2;      // q sub-tile / kv half
  const int l32 = lane & 31, hf = lane >> 5;
  const int q0 = qt << 7;

  // Q B-operand frags: n = q = l32, k = hf*8 + j (per 16-wide k-step)
  short8 qf[4];
  {
    const ushort* qp = qb + (size_t)(b * SEQ + q0 + qw * 32 + l32) * DIM
                          + h * HD + hf * 8;
#pragma unroll
    for (int ks = 0; ks < 4; ++ks) qf[ks] = *(const short8*)(qp + ks * 16);
  }

  // stage K [128 kv][64 d] and permuted V^T [64 d][128 kv] into buffer PB
  // (512 threads: 2 iterations cover each 1024x16B tile; linear dest)
#define STAGE_ATTN(PB, KV0)                                                    \
  _Pragma("unroll")                                                            \
  for (int i = 0; i < 2; ++i) {                                                \
    int s = i * 512 + tid;                                                     \
    int rowK = s >> 3, cgK = (s & 7) ^ (rowK & 7);                             \
    gload16(&kb[(size_t)(b * SEQ + (KV0) + rowK) * (NG * HD) + g * HD + cgK * 8],\
            &SM[PB][(size_t)(i * 512 + (wave << 6)) * 8]);                     \
    int rowV = s >> 4, cgV = (s & 15) ^ (rowV & 7);                            \
    gload16(&vt[((size_t)(b * NG + g) * HD + rowV) * SEQ + (KV0) + cgV * 8],   \
            &SM[PB][8192 + (size_t)(i * 512 + (wave << 6)) * 8]);              \
  }

  f32x16 O0 = {0,0,0,0,0,0,0,0,0,0,0,0,0,0,0,0};  // O^T[d 0..31][q], kv-half kh
  f32x16 O1 = {0,0,0,0,0,0,0,0,0,0,0,0,0,0,0,0};  // O^T[d 32..63][q]
  float lsum = 0.f;

  STAGE_ATTN(0, 0)
  __syncthreads();   // vmcnt(0) drain: tile 0 resident

  for (int kv0 = 0; kv0 < SEQ; kv0 += 128) {
    const int pb = (kv0 >> 7) & 1;
    if (kv0 + 128 < SEQ) { STAGE_ATTN(1 - pb, kv0 + 128) }  // async, in flight
    const ushort* Ks = SM[pb] + kh * 64 * 64;   // this wave's 64 kv rows
    const ushort* Vs = SM[pb] + 8192;

    // S^T = K Q^T over this wave's kv half: 2x 32-kv blocks
    f32x16 S0 = {0,0,0,0,0,0,0,0,0,0,0,0,0,0,0,0};
    f32x16 S1 = {0,0,0,0,0,0,0,0,0,0,0,0,0,0,0,0};
    __builtin_amdgcn_s_setprio(1);
#pragma unroll
    for (int ks = 0; ks < 4; ++ks) {
      short8 k0 = *(const short8*)&Ks[( 0 + l32) * 64 + (((ks*2+hf) ^ (l32 & 7)) * 8)];
      short8 k1 = *(const short8*)&Ks[(32 + l32) * 64 + (((ks*2+hf) ^ (l32 & 7)) * 8)];
      S0 = __builtin_amdgcn_mfma_f32_32x32x16_bf16(k0, qf[ks], S0, 0, 0, 0);
      S1 = __builtin_amdgcn_mfma_f32_32x32x16_bf16(k1, qf[ks], S1, 0, 0, 0);
    }
    __builtin_amdgcn_s_setprio(0);

    // softmax + PV over this wave's 4 kv-16 blocks
#pragma unroll
    for (int t = 0; t < 4; ++t) {
      const f32x16& Ss = (t < 2) ? S0 : S1;
      int base = (t & 1) * 8;
      float e0 = EXP2F(Ss[base + 0]), e1 = EXP2F(Ss[base + 1]);
      float e2 = EXP2F(Ss[base + 2]), e3 = EXP2F(Ss[base + 3]);
      float e4 = EXP2F(Ss[base + 4]), e5 = EXP2F(Ss[base + 5]);
      float e6 = EXP2F(Ss[base + 6]), e7 = EXP2F(Ss[base + 7]);
      lsum += ((e0 + e1) + (e2 + e3)) + ((e4 + e5) + (e6 + e7));
      uint4v pw;
      pw[0] = packtr(e0, e1); pw[1] = packtr(e2, e3);
      pw[2] = packtr(e4, e5); pw[3] = packtr(e6, e7);
      short8 pf = __builtin_bit_cast(short8, pw);
      int ch = (kh * 4 + t) * 2 + hf;           // global kv-16 block col-group
      short8 v0 = *(const short8*)&Vs[( 0 + l32) * 128 + ((ch ^ (l32 & 7)) * 8)];
      short8 v1 = *(const short8*)&Vs[(32 + l32) * 128 + ((ch ^ (l32 & 7)) * 8)];
      __builtin_amdgcn_s_setprio(1);
      O0 = __builtin_amdgcn_mfma_f32_32x32x16_bf16(v0, pf, O0, 0, 0, 0);
      O1 = __builtin_amdgcn_mfma_f32_32x32x16_bf16(v1, pf, O1, 0, 0, 0);
      __builtin_amdgcn_s_setprio(0);
    }
    // single per-tile barrier: drains this tile's prefetch DMA (vmcnt) and
    // fences all waves' LDS reads before buffer 1-pb is restaged next iter
    __syncthreads();
  }

  // ---- kv-half combine: plain addition (no-max softmax). kh==1 waves park
  // their partials in LDS; kh==0 waves add and finish. red region starts after
  // the 4 Lw transpose regions (byte 17408) — disjoint, no extra barrier.
  float* red = (float*)((ushort*)SM + 4 * 32 * 68);
  {
    float* me = red + (size_t)(qw * 64 + lane) * 33;   // stride 33: bank-clean
    if (kh == 1) {
#pragma unroll
      for (int r = 0; r < 16; ++r) { me[r] = O0[r]; me[16 + r] = O1[r]; }
      me[32] = lsum;
    }
  }
  __syncthreads();
  if (kh == 1) return;   // no barriers after this point

  {
    const float* pr = red + (size_t)(qw * 64 + lane) * 33;
#pragma unroll
    for (int r = 0; r < 16; ++r) { O0[r] += pr[r]; O1[r] += pr[16 + r]; }
    lsum += pr[32];
  }

  float inv = 1.f / (lsum + __shfl_xor(lsum, 32, 64));

  // transpose O^T -> O via LDS (wave-private region, stride 68)
  ushort* Lw = (ushort*)SM + qw * (32 * 68);
#pragma unroll
  for (int r = 0; r < 16; r += 2) {
    int d0 = (r & 3) + 8 * (r >> 2) + 4 * hf;
    *(uint*)&Lw[l32 * 68 + d0]      = pack2(O0[r] * inv, O0[r + 1] * inv);
    *(uint*)&Lw[l32 * 68 + 32 + d0] = pack2(O1[r] * inv, O1[r + 1] * inv);
  }
  // each lane writes row q=l32, d-half hf (wave-private: no barrier needed)
  ushort* orow = op + (size_t)(b * SEQ + q0 + qw * 32 + l32) * DIM
                    + h * HD + hf * 32;
#pragma unroll
  for (int c = 0; c < 4; ++c) {
    short4v lo = *(const short4v*)&Lw[l32 * 68 + hf * 32 + c * 8];
    short4v hi = *(const short4v*)&Lw[l32 * 68 + hf * 32 + c * 8 + 4];
    short8 o = {lo[0], lo[1], lo[2], lo[3], hi[0], hi[1], hi[2], hi[3]};
    *(short8*)(orow + c * 8) = o;
  }
#undef STAGE_ATTN
}

extern "C" void kernel_launch(void* const* d_in, const int* in_sizes, int n_in,
                              void* d_out, int out_size, void* d_ws, size_t ws_size,
                              hipStream_t stream) {
  (void)in_sizes; (void)n_in; (void)out_size; (void)ws_size;
  const float* query = (const float*)d_in[0];
  const float* key   = (const float*)d_in[1];
  const float* value = (const float*)d_in[2];
  const float* Wq = (const float*)d_in[4];
  const float* bq = (const float*)d_in[5];
  const float* Wk = (const float*)d_in[6];
  const float* bk = (const float*)d_in[7];
  const float* Wv = (const float*)d_in[8];
  const float* bv = (const float*)d_in[9];
  const float* qnw = (const float*)d_in[10];
  const float* qnb = (const float*)d_in[11];
  const float* knw = (const float*)d_in[12];
  const float* knb = (const float*)d_in[13];
  const float* Wo = (const float*)d_in[14];
  const float* bo = (const float*)d_in[15];
  float* out = (float*)d_out;

  const size_t MD = (size_t)NB * SEQ * DIM;        // 4M elements
  const size_t WD = (size_t)DIM * DIM;             // 1M
  const size_t KD = (size_t)(NG * HD) * DIM;       // 256K
  const size_t MK = (size_t)NB * SEQ * NG * HD;    // 1M

  // ws (29 MB):
  ushort* qA  = (ushort*)d_ws;        // 8 MB
  ushort* kA  = qA  + MD;             // 8 MB (later: attention output)
  ushort* WqB = kA  + MD;             // 2 MB
  ushort* WkB = WqB + WD;             // 0.5 MB
  ushort* WvB = WkB + KD;             // 0.5 MB
  ushort* WoB = WvB + KD;             // 2 MB
  ushort* Qb  = WoB + WD;             // 8 MB
  // d_out as scratch (12 of 16 MB), all dead before gemm_out writes:
  ushort* vA  = (ushort*)d_out;       // 8 MB
  ushort* kbb = vA  + MD;             // 2 MB
  ushort* vtb = kbb + MK;             // 2 MB
  ushort* attnO = kA;

  dim3 blk(256);
  CastArgs ca;
  ca.seg[0] = { query, qA, 2048 };
  ca.seg[1] = { key,   kA, 2048 };
  ca.seg[2] = { value, vA, 2048 };
  ca.seg[3] = { Wq, WqB, 512 };
  ca.seg[4] = { Wk, WkB, 128 };
  ca.seg[5] = { Wv, WvB, 128 };
  ca.seg[6] = { Wo, WoB, 512 };
  castN<<<dim3(7424), blk, 0, stream>>>(ca);
  gemm_qkv<<<dim3(768), dim3(512), 0, stream>>>(
      qA, kA, vA, WqB, WkB, WvB, bq, bk, bv,
      qnw, qnb, knw, knb, Qb, kbb, vtb);
  attn_mfma4<<<dim3(512), dim3(512), 0, stream>>>(Qb, kbb, vtb, attnO);
  gemm_out<<<dim3(512), dim3(512), 0, stream>>>(attnO, WoB, bo, out);
}